// Round 1
// baseline (2049.005 us; speedup 1.0000x reference)
//
#include <hip/hip_runtime.h>

// Quantum classifier forward: 14 qubits, batch 4096, 6 StronglyEntanglingLayers.
// Strategy:
//  - one 1024-thread block per sample; full 2^14 complex64 state in LDS (128 KiB)
//  - RY encoding fused into product-state init (no gate passes)
//  - CNOT layers absorbed into a compile-time GF(2) index transform (G, H=G^-1);
//    Rot gates become XOR-mask butterflies; <Z> signs come from rows of G_final
//  - 2 Rot gates fused per pass (quad butterfly): 42 passes total

#define NQ      14
#define NLAYERS 6
#define NPASS   42          // 6 layers * 7 qubit-pairs
#define NSTATE  16384
#define BLOCK   1024

// ---------------- compile-time GF(2) linear algebra ----------------
struct GF2 { unsigned short r[NQ]; };   // r[b] = row b as column bitmask

constexpr GF2 gf2_id() {
    GF2 m{}; for (int i = 0; i < NQ; ++i) m.r[i] = (unsigned short)(1u << i); return m;
}
constexpr GF2 gf2_mul(GF2 A, GF2 B) {   // (AB) row i = XOR of B rows selected by A row i
    GF2 C{};
    for (int i = 0; i < NQ; ++i) {
        unsigned v = 0;
        for (int k = 0; k < NQ; ++k) if ((A.r[i] >> k) & 1) v ^= B.r[k];
        C.r[i] = (unsigned short)v;
    }
    return C;
}
// CNOT(control c, target t): flat-index bit of qubit q is (13-q).
// F(y): bit (13-t) ^= bit (13-c)
constexpr GF2 cnotF(int c, int t) {
    GF2 F = gf2_id();
    F.r[13 - t] = (unsigned short)((1u << (13 - t)) | (1u << (13 - c)));
    return F;
}

struct Tables {
    unsigned int m1[NPASS], r1[NPASS], m2[NPASS], r2[NPASS];
    int blo[NPASS], bhi[NPASS];
    unsigned int er0, er1;
};

constexpr Tables make_tables() {
    Tables T{};
    GF2 G = gf2_id(), H = gf2_id();   // storage->logical map and inverse
    for (int l = 0; l < NLAYERS; ++l) {
        // Rot gates of layer l use current (G, H)
        for (int i = 0; i < 7; ++i) {
            const int q1 = 2 * i, q2 = 2 * i + 1;
            const int b1 = 13 - q1, b2 = 13 - q2;
            unsigned m1 = 0, m2 = 0;
            for (int r = 0; r < NQ; ++r) {            // columns of H
                m1 |= ((unsigned)((H.r[r] >> b1) & 1u)) << r;
                m2 |= ((unsigned)((H.r[r] >> b2) & 1u)) << r;
            }
            const unsigned rr1 = G.r[b1], rr2 = G.r[b2];
            // choose enumeration bits (zeroed in base index): need 2x2 GF2 det == 1,
            // prefer high bits (keeps low lane bits contiguous -> fewer bank conflicts)
            int bestlo = -1, besthi = -1, best = -1;
            for (int a = 0; a < NQ; ++a)
                for (int b = 0; b < NQ; ++b) {
                    if (a == b) continue;
                    unsigned det = (((m1 >> a) & 1u) * ((m2 >> b) & 1u)) ^
                                   (((m1 >> b) & 1u) * ((m2 >> a) & 1u));
                    if (det & 1u) {
                        int lo = a < b ? a : b, hi = a < b ? b : a;
                        int sc = lo * 16 + hi;
                        if (sc > best) { best = sc; bestlo = lo; besthi = hi; }
                    }
                }
            const int pp = l * 7 + i;
            T.m1[pp] = m1; T.r1[pp] = rr1; T.m2[pp] = m2; T.r2[pp] = rr2;
            T.blo[pp] = bestlo; T.bhi[pp] = besthi;
        }
        // absorb this layer's CNOT chain: state_new = state_old ∘ C,
        // C = F_{q=0} · F_{q=1} · ... · F_{q=13};  G' = C^-1 G,  H' = H C
        const int r = (l % (NQ - 1)) + 1;
        GF2 C = gf2_id(), Ci = gf2_id();
        for (int q = 0; q < NQ; ++q) {
            GF2 F = cnotF(q, (q + r) % NQ);
            C  = gf2_mul(C, F);    // left-to-right product
            Ci = gf2_mul(F, Ci);   // reversed product = inverse
        }
        G = gf2_mul(Ci, G);
        H = gf2_mul(H, C);
    }
    T.er0 = G.r[13];   // qubit 0 -> bit 13
    T.er1 = G.r[12];   // qubit 1 -> bit 12
    return T;
}

constexpr Tables TBL = make_tables();

// complex 2x2 matvec: (o0,o1) = [[g0+ig1, g2+ig3],[g4+ig5, g6+ig7]] . (a0,a1)
__device__ __forceinline__ void cmat2(const float* __restrict__ g,
                                      float2 a0, float2 a1,
                                      float2& o0, float2& o1) {
    o0.x = g[0] * a0.x - g[1] * a0.y + g[2] * a1.x - g[3] * a1.y;
    o0.y = g[0] * a0.y + g[1] * a0.x + g[2] * a1.y + g[3] * a1.x;
    o1.x = g[4] * a0.x - g[5] * a0.y + g[6] * a1.x - g[7] * a1.y;
    o1.y = g[4] * a0.y + g[5] * a0.x + g[6] * a1.y + g[7] * a1.x;
}

extern "C" __global__ void __launch_bounds__(BLOCK)
qc_kernel(const float* __restrict__ x, const float* __restrict__ w,
          float* __restrict__ out) {
    extern __shared__ float lds[];
    float2* st    = reinterpret_cast<float2*>(lds);   // 16384 complex (128 KiB)
    float*  gates = lds + 2 * NSTATE;                 // 84 gates * 8 floats
    float*  enc   = gates + 8 * 84;                   // 14 * (cos, sin)
    float*  red   = enc + 28;                         // 16 waves * 2

    const unsigned t = threadIdx.x;
    const unsigned s = blockIdx.x;

    // --- per-block precompute: Rot matrices (shared weights) + encoding angles ---
    if (t < 84) {
        const float phi = w[3 * t + 0], th = w[3 * t + 1], om = w[3 * t + 2];
        const float ct = cosf(0.5f * th), stt = sinf(0.5f * th);
        const float aa = 0.5f * (phi + om), bb = 0.5f * (phi - om);
        const float ca = cosf(aa), sa = sinf(aa);
        const float cb = cosf(bb), sb = sinf(bb);
        float* g = gates + 8 * t;
        g[0] =  ca * ct;  g[1] = -sa * ct;    // u00 = e^{-i(phi+om)/2} cos(th/2)
        g[2] = -cb * stt; g[3] = -sb * stt;   // u01 = -e^{+i(phi-om)/2} sin(th/2)
        g[4] =  cb * stt; g[5] = -sb * stt;   // u10 = e^{-i(phi-om)/2} sin(th/2)
        g[6] =  ca * ct;  g[7] =  sa * ct;    // u11 = e^{+i(phi+om)/2} cos(th/2)
    }
    if (t < NQ) {
        const float h = x[s * NQ + t] * 1.57079632679489662f;  // theta/2 = x*pi/2
        enc[2 * t]     = cosf(h);
        enc[2 * t + 1] = sinf(h);
    }
    __syncthreads();

    // --- init: product state from RY encoding (qubit q <-> index bit 13-q) ---
    {
        float pr = 1.0f;
        #pragma unroll
        for (int b = 0; b < 10; ++b) pr *= enc[2 * (13 - b) + ((t >> b) & 1u)];
        #pragma unroll
        for (int i = 0; i < 16; ++i) {
            float v = pr;
            #pragma unroll
            for (int b = 0; b < 4; ++b) v *= enc[2 * (3 - b) + ((i >> b) & 1)];
            st[t + (i << 10)] = make_float2(v, 0.0f);
        }
    }
    __syncthreads();

    // --- 42 fused gate passes ---
    #pragma unroll 1
    for (int pp = 0; pp < NPASS; ++pp) {
        const unsigned m1 = TBL.m1[pp], rr1 = TBL.r1[pp];
        const unsigned m2 = TBL.m2[pp], rr2 = TBL.r2[pp];
        const unsigned blo = (unsigned)TBL.blo[pp], bhi = (unsigned)TBL.bhi[pp];

        float g0[8], g1[8];
        const float* gp = gates + 16 * pp;   // gates (l,2i) and (l,2i+1) are contiguous
        #pragma unroll
        for (int e = 0; e < 8; ++e) { g0[e] = gp[e]; g1[e] = gp[8 + e]; }

        unsigned base[4];
        float2 A[4][4];
        // phase A: compute addresses, issue all 16 loads (hide LDS latency)
        #pragma unroll
        for (int k = 0; k < 4; ++k) {
            unsigned j = t + ((unsigned)k << 10);               // 12-bit quad index
            unsigned p = ((j >> blo) << (blo + 1)) | (j & ((1u << blo) - 1u));
            p = ((p >> bhi) << (bhi + 1)) | (p & ((1u << bhi) - 1u));
            const unsigned s1 = (unsigned)(__popc((int)(p & rr1)) & 1);
            const unsigned s2 = (unsigned)(__popc((int)(p & rr2)) & 1);
            const unsigned b = p ^ ((0u - s1) & m1) ^ ((0u - s2) & m2);
            base[k] = b;
            A[k][0] = st[b];            // x_q1=0, x_q2=0
            A[k][1] = st[b ^ m1];       // x_q1=1
            A[k][2] = st[b ^ m2];       // x_q2=1
            A[k][3] = st[b ^ m1 ^ m2];
        }
        // phase B: apply U(q1) then U(q2), write back
        #pragma unroll
        for (int k = 0; k < 4; ++k) {
            float2 B0, B1, B2, B3, C0, C1, C2, C3;
            cmat2(g0, A[k][0], A[k][1], B0, B1);
            cmat2(g0, A[k][2], A[k][3], B2, B3);
            cmat2(g1, B0, B2, C0, C2);
            cmat2(g1, B1, B3, C1, C3);
            const unsigned b = base[k];
            st[b] = C0; st[b ^ m1] = C1; st[b ^ m2] = C2; st[b ^ m1 ^ m2] = C3;
        }
        __syncthreads();
    }

    // --- <Z_0>, <Z_1> via rows of final G ---
    const unsigned er0 = TBL.er0, er1 = TBL.er1;
    float z0 = 0.0f, z1 = 0.0f;
    #pragma unroll
    for (int i = 0; i < 16; ++i) {
        const unsigned p = t + ((unsigned)i << 10);
        const float2 a = st[p];
        const float pr = a.x * a.x + a.y * a.y;
        z0 += (__popc((int)(p & er0)) & 1) ? -pr : pr;
        z1 += (__popc((int)(p & er1)) & 1) ? -pr : pr;
    }
    #pragma unroll
    for (int off = 32; off > 0; off >>= 1) {
        z0 += __shfl_down(z0, off, 64);
        z1 += __shfl_down(z1, off, 64);
    }
    if ((t & 63u) == 0u) { red[(t >> 6) * 2] = z0; red[(t >> 6) * 2 + 1] = z1; }
    __syncthreads();
    if (t == 0) {
        float a0 = 0.0f, a1 = 0.0f;
        #pragma unroll
        for (int k = 0; k < 16; ++k) { a0 += red[2 * k]; a1 += red[2 * k + 1]; }
        out[2 * s]     = a0;
        out[2 * s + 1] = a1;
    }
}

extern "C" void kernel_launch(void* const* d_in, const int* in_sizes, int n_in,
                              void* d_out, int out_size, void* d_ws, size_t ws_size,
                              hipStream_t stream) {
    const float* x = (const float*)d_in[0];   // (4096, 14) f32
    const float* w = (const float*)d_in[1];   // (6, 14, 3) f32
    float* out = (float*)d_out;               // (4096, 2) f32
    const int B = in_sizes[0] / NQ;
    const size_t lds_bytes = (size_t)(2 * NSTATE + 8 * 84 + 28 + 32) * sizeof(float); // 134000 B
    (void)hipFuncSetAttribute(reinterpret_cast<const void*>(qc_kernel),
                              hipFuncAttributeMaxDynamicSharedMemorySize,
                              (int)lds_bytes);
    qc_kernel<<<B, BLOCK, lds_bytes, stream>>>(x, w, out);
}

// Round 2
// 1067.518 us; speedup vs baseline: 1.9194x; 1.9194x over previous
//
#include <hip/hip_runtime.h>

// Quantum classifier forward: 14 qubits, batch 4096, 6 StronglyEntanglingLayers.
// Round 2:
//  - 4-qubit fused passes (24 total, was 42): one 16-amp coset per thread
//  - gate matrices precomputed to global ws by a pre-kernel -> wave-uniform
//    s_load into SGPRs (no LDS broadcast reads, no per-pass VALU for gates)
//  - compile-time search of enumeration bits for LDS bank-conflict-free
//    access (lane -> bank-pair map must have GF(2) rank 4)
//  - CNOTs absorbed into compile-time GF(2) index transform (as Round 1)

#define NQ      14
#define NLAYERS 6
#define NPASSES 24          // 4 per layer (4+4+4+2 qubits)
#define NSTATE  16384
#define BLOCK   1024

// ---------------- compile-time GF(2) linear algebra ----------------
struct GF2 { unsigned short r[NQ]; };   // r[b] = row b as column bitmask

constexpr GF2 gf2_id() {
    GF2 m{}; for (int i = 0; i < NQ; ++i) m.r[i] = (unsigned short)(1u << i); return m;
}
constexpr GF2 gf2_mul(GF2 A, GF2 B) {
    GF2 C{};
    for (int i = 0; i < NQ; ++i) {
        unsigned v = 0;
        for (int k = 0; k < NQ; ++k) if ((A.r[i] >> k) & 1) v ^= B.r[k];
        C.r[i] = (unsigned short)v;
    }
    return C;
}
constexpr GF2 cnotF(int c, int t) {     // flat-index bit of qubit q is (13-q)
    GF2 F = gf2_id();
    F.r[13 - t] = (unsigned short)((1u << (13 - t)) | (1u << (13 - c)));
    return F;
}

struct Pass {
    unsigned m[4];    // XOR masks (columns of H) for the pass's qubits
    unsigned rr[4];   // role rows (rows of G)
    int a[4];         // enumeration (zero-insertion) bit positions, ascending
    int nq;           // 4 or 2
};
struct Tables { Pass ps[NPASSES]; unsigned er0, er1; };

// det of selection matrix + lane->bank rank for a candidate bit choice
constexpr int try_combo(const unsigned* m, const unsigned* rr, int k, const int* asc) {
    unsigned rows[4] = {0, 0, 0, 0};
    for (int i = 0; i < k; ++i) {
        unsigned rv = 0;
        for (int j = 0; j < k; ++j) rv |= ((m[i] >> asc[j]) & 1u) << j;
        rows[i] = rv;
    }
    unsigned used = 0;
    for (int j = 0; j < k; ++j) {             // Gaussian elim over GF(2)
        int pick = -1;
        for (int i = 0; i < k; ++i)
            if (!((used >> i) & 1) && ((rows[i] >> j) & 1)) { pick = i; break; }
        if (pick < 0) return -1;              // singular -> not a bijection
        used |= 1u << pick;
        for (int i = 0; i < k; ++i)
            if (i != pick && ((rows[i] >> j) & 1)) rows[i] ^= rows[pick];
    }
    // rank of lane-bit -> (base & 15) map; rank 4 => conflict-free b64
    unsigned bas[4] = {0, 0, 0, 0}; int r = 0;
    for (int e = 0; e < 6; ++e) {
        unsigned p = 1u << e;
        for (int i = 0; i < k; ++i)
            p = ((p >> asc[i]) << (asc[i] + 1)) | (p & ((1u << asc[i]) - 1u));
        unsigned b = p;
        for (int i = 0; i < k; ++i) {
            unsigned s = (unsigned)(__builtin_popcount(p & rr[i]) & 1);
            b ^= (0u - s) & m[i];
        }
        unsigned c = b & 15u;
        for (int bit = 3; bit >= 0; --bit) {
            if (!((c >> bit) & 1u)) continue;
            if (bas[bit]) c ^= bas[bit];
            else { bas[bit] = c; ++r; break; }
        }
    }
    return r;
}

constexpr Pass pick_bits(Pass P) {
    const int k = P.nq;
    int best = -2;
    if (k == 4) {
        for (int a0 = 13; a0 >= 3 && best < 4; --a0)
        for (int a1 = a0 - 1; a1 >= 2 && best < 4; --a1)
        for (int a2 = a1 - 1; a2 >= 1 && best < 4; --a2)
        for (int a3 = a2 - 1; a3 >= 0 && best < 4; --a3) {
            const int asc[4] = {a3, a2, a1, a0};
            const int r = try_combo(P.m, P.rr, 4, asc);
            if (r > best) { best = r; P.a[0]=a3; P.a[1]=a2; P.a[2]=a1; P.a[3]=a0; }
        }
    } else {
        for (int a0 = 13; a0 >= 1 && best < 4; --a0)
        for (int a1 = a0 - 1; a1 >= 0 && best < 4; --a1) {
            const int asc[2] = {a1, a0};
            const int r = try_combo(P.m, P.rr, 2, asc);
            if (r > best) { best = r; P.a[0]=a1; P.a[1]=a0; P.a[2]=0; P.a[3]=0; }
        }
    }
    return P;
}

constexpr Tables make_tables() {
    Tables T{};
    GF2 G = gf2_id(), H = gf2_id();   // storage->logical map and inverse
    for (int l = 0; l < NLAYERS; ++l) {
        for (int g = 0; g < 4; ++g) {
            Pass P{};
            const int k = (g < 3) ? 4 : 2;
            P.nq = k;
            for (int i = 0; i < k; ++i) {
                const int q = 4 * g + i, bit = 13 - q;
                unsigned mm = 0;
                for (int r2 = 0; r2 < NQ; ++r2)
                    mm |= ((unsigned)((H.r[r2] >> bit) & 1u)) << r2;
                P.m[i] = mm;
                P.rr[i] = G.r[bit];
            }
            T.ps[l * 4 + g] = pick_bits(P);
        }
        // absorb this layer's CNOT chain: G' = C^-1 G, H' = H C
        const int r = (l % (NQ - 1)) + 1;
        GF2 C = gf2_id(), Ci = gf2_id();
        for (int q = 0; q < NQ; ++q) {
            GF2 F = cnotF(q, (q + r) % NQ);
            C  = gf2_mul(C, F);
            Ci = gf2_mul(F, Ci);
        }
        G = gf2_mul(Ci, G);
        H = gf2_mul(H, C);
    }
    T.er0 = G.r[13];
    T.er1 = G.r[12];
    return T;
}

constexpr Tables TBL = make_tables();

// SU(2) gate application to an amplitude pair: 16 VALU ops (mul + 3*fma per comp)
__device__ __forceinline__ void su2(const float* __restrict__ g, float2& p, float2& q) {
    const float x0 = p.x, y0 = p.y, x1 = q.x, y1 = q.y;
    float2 o0, o1;
    o0.x = fmaf(g[0], x0, fmaf(-g[1], y0, fmaf(g[2], x1, -g[3] * y1)));
    o0.y = fmaf(g[0], y0, fmaf( g[1], x0, fmaf(g[2], y1,  g[3] * x1)));
    o1.x = fmaf(g[4], x0, fmaf(-g[5], y0, fmaf(g[6], x1, -g[7] * y1)));
    o1.y = fmaf(g[4], y0, fmaf( g[5], x0, fmaf(g[6], y1,  g[7] * x1)));
    p = o0; q = o1;
}

// ---- 4-gate fused pass: each thread owns one 16-amplitude coset ----
__device__ __forceinline__ void do4(float2* __restrict__ st, const Pass& P,
                                    const float* __restrict__ gp, unsigned t) {
    const unsigned m0 = P.m[0], m1 = P.m[1], m2 = P.m[2], m3 = P.m[3];
    const unsigned r0 = P.rr[0], r1 = P.rr[1], r2 = P.rr[2], r3 = P.rr[3];
    const int a0 = P.a[0], a1 = P.a[1], a2 = P.a[2], a3 = P.a[3];

    float gl[32];
    #pragma unroll
    for (int e = 0; e < 32; ++e) gl[e] = gp[e];   // wave-uniform -> s_load

    unsigned p = t;
    p = ((p >> a0) << (a0 + 1)) | (p & ((1u << a0) - 1u));
    p = ((p >> a1) << (a1 + 1)) | (p & ((1u << a1) - 1u));
    p = ((p >> a2) << (a2 + 1)) | (p & ((1u << a2) - 1u));
    p = ((p >> a3) << (a3 + 1)) | (p & ((1u << a3) - 1u));
    unsigned b = p;
    b ^= (0u - (unsigned)(__popc(p & r0) & 1)) & m0;
    b ^= (0u - (unsigned)(__popc(p & r1) & 1)) & m1;
    b ^= (0u - (unsigned)(__popc(p & r2) & 1)) & m2;
    b ^= (0u - (unsigned)(__popc(p & r3) & 1)) & m3;

    float2 v[16];
    #pragma unroll
    for (int c = 0; c < 16; ++c) {
        const unsigned mc = ((c & 1) ? m0 : 0u) ^ ((c & 2) ? m1 : 0u) ^
                            ((c & 4) ? m2 : 0u) ^ ((c & 8) ? m3 : 0u);
        v[c] = st[b ^ mc];
    }
    #pragma unroll
    for (int i = 0; i < 4; ++i) {
        #pragma unroll
        for (int c = 0; c < 16; ++c)
            if (!(c & (1 << i)))
                su2(gl + 8 * i, v[c], v[c | (1 << i)]);
    }
    #pragma unroll
    for (int c = 0; c < 16; ++c) {
        const unsigned mc = ((c & 1) ? m0 : 0u) ^ ((c & 2) ? m1 : 0u) ^
                            ((c & 4) ? m2 : 0u) ^ ((c & 8) ? m3 : 0u);
        st[b ^ mc] = v[c];
    }
}

// ---- 2-gate pass (qubits 12,13): 4 quads per thread ----
__device__ __forceinline__ void do2(float2* __restrict__ st, const Pass& P,
                                    const float* __restrict__ gp, unsigned t) {
    const unsigned m0 = P.m[0], m1 = P.m[1];
    const unsigned r0 = P.rr[0], r1 = P.rr[1];
    const int a0 = P.a[0], a1 = P.a[1];

    float gl[16];
    #pragma unroll
    for (int e = 0; e < 16; ++e) gl[e] = gp[e];

    unsigned bb[4];
    float2 v[4][4];
    #pragma unroll
    for (int k = 0; k < 4; ++k) {
        unsigned j = t + ((unsigned)k << 10);
        unsigned p = ((j >> a0) << (a0 + 1)) | (j & ((1u << a0) - 1u));
        p = ((p >> a1) << (a1 + 1)) | (p & ((1u << a1) - 1u));
        unsigned b = p;
        b ^= (0u - (unsigned)(__popc(p & r0) & 1)) & m0;
        b ^= (0u - (unsigned)(__popc(p & r1) & 1)) & m1;
        bb[k] = b;
        v[k][0] = st[b];
        v[k][1] = st[b ^ m0];
        v[k][2] = st[b ^ m1];
        v[k][3] = st[b ^ m0 ^ m1];
    }
    #pragma unroll
    for (int k = 0; k < 4; ++k) {
        su2(gl,     v[k][0], v[k][1]);
        su2(gl,     v[k][2], v[k][3]);
        su2(gl + 8, v[k][0], v[k][2]);
        su2(gl + 8, v[k][1], v[k][3]);
        const unsigned b = bb[k];
        st[b]            = v[k][0];
        st[b ^ m0]       = v[k][1];
        st[b ^ m1]       = v[k][2];
        st[b ^ m0 ^ m1]  = v[k][3];
    }
}

// ---- pre-kernel: Rot matrices into workspace (read via s_load later) ----
__global__ void gate_kernel(const float* __restrict__ w, float* __restrict__ gws) {
    const int t = threadIdx.x;
    if (t < NLAYERS * NQ) {
        const float phi = w[3 * t + 0], th = w[3 * t + 1], om = w[3 * t + 2];
        const float ct = cosf(0.5f * th), stt = sinf(0.5f * th);
        const float aa = 0.5f * (phi + om), bb = 0.5f * (phi - om);
        const float ca = cosf(aa), sa = sinf(aa);
        const float cb = cosf(bb), sb = sinf(bb);
        float* g = gws + 8 * t;
        g[0] =  ca * ct;  g[1] = -sa * ct;    // u00
        g[2] = -cb * stt; g[3] = -sb * stt;   // u01
        g[4] =  cb * stt; g[5] = -sb * stt;   // u10
        g[6] =  ca * ct;  g[7] =  sa * ct;    // u11
    }
}

extern "C" __global__ void __launch_bounds__(BLOCK)
qc_kernel(const float* __restrict__ x, const float* __restrict__ gws,
          float* __restrict__ out) {
    extern __shared__ float lds[];
    float2* st  = reinterpret_cast<float2*>(lds);   // 16384 complex (128 KiB)
    float*  enc = lds + 2 * NSTATE;                 // 14 * (cos, sin)
    float*  red = enc + 28;                         // 16 waves * 2

    const unsigned t = threadIdx.x;
    const unsigned s = blockIdx.x;

    if (t < NQ) {
        const float h = x[s * NQ + t] * 1.57079632679489662f;  // theta/2
        enc[2 * t]     = cosf(h);
        enc[2 * t + 1] = sinf(h);
    }
    __syncthreads();

    // --- init: product state from RY encoding (qubit q <-> index bit 13-q) ---
    {
        float pr = 1.0f;
        #pragma unroll
        for (int b = 0; b < 10; ++b) pr *= enc[2 * (13 - b) + ((t >> b) & 1u)];
        #pragma unroll
        for (int i = 0; i < 16; ++i) {
            float v = pr;
            #pragma unroll
            for (int b = 0; b < 4; ++b) v *= enc[2 * (3 - b) + ((i >> b) & 1)];
            st[t + (i << 10)] = make_float2(v, 0.0f);
        }
    }
    __syncthreads();

    // --- 24 fused gate passes ---
    #pragma unroll 1
    for (int l = 0; l < NLAYERS; ++l) {
        #pragma unroll 1
        for (int g = 0; g < 4; ++g) {
            const Pass& P = TBL.ps[l * 4 + g];
            const float* gp = gws + (size_t)(l * NQ + g * 4) * 8;
            if (g < 3) do4(st, P, gp, t);
            else       do2(st, P, gp, t);
            __syncthreads();
        }
    }

    // --- <Z_0>, <Z_1> via rows of final G ---
    const unsigned er0 = TBL.er0, er1 = TBL.er1;
    float z0 = 0.0f, z1 = 0.0f;
    #pragma unroll
    for (int i = 0; i < 16; ++i) {
        const unsigned p = t + ((unsigned)i << 10);
        const float2 a = st[p];
        const float pr = a.x * a.x + a.y * a.y;
        z0 += (__popc((int)(p & er0)) & 1) ? -pr : pr;
        z1 += (__popc((int)(p & er1)) & 1) ? -pr : pr;
    }
    #pragma unroll
    for (int off = 32; off > 0; off >>= 1) {
        z0 += __shfl_down(z0, off, 64);
        z1 += __shfl_down(z1, off, 64);
    }
    if ((t & 63u) == 0u) { red[(t >> 6) * 2] = z0; red[(t >> 6) * 2 + 1] = z1; }
    __syncthreads();
    if (t == 0) {
        float a0 = 0.0f, a1 = 0.0f;
        #pragma unroll
        for (int k = 0; k < 16; ++k) { a0 += red[2 * k]; a1 += red[2 * k + 1]; }
        out[2 * s]     = a0;
        out[2 * s + 1] = a1;
    }
}

extern "C" void kernel_launch(void* const* d_in, const int* in_sizes, int n_in,
                              void* d_out, int out_size, void* d_ws, size_t ws_size,
                              hipStream_t stream) {
    const float* x = (const float*)d_in[0];   // (4096, 14) f32
    const float* w = (const float*)d_in[1];   // (6, 14, 3) f32
    float* out = (float*)d_out;               // (4096, 2) f32
    float* gws = (float*)d_ws;                // 84 * 8 floats
    const int B = in_sizes[0] / NQ;

    gate_kernel<<<1, 128, 0, stream>>>(w, gws);

    const size_t lds_bytes = (size_t)(2 * NSTATE + 28 + 32) * sizeof(float); // 131312 B
    (void)hipFuncSetAttribute(reinterpret_cast<const void*>(qc_kernel),
                              hipFuncAttributeMaxDynamicSharedMemorySize,
                              (int)lds_bytes);
    qc_kernel<<<B, BLOCK, lds_bytes, stream>>>(x, gws, out);
}